// Round 2
// baseline (78.325 us; speedup 1.0000x reference)
//
#include <hip/hip_runtime.h>
#include <stdint.h>

typedef _Float16 f16x8 __attribute__((ext_vector_type(8)));
typedef float    f32x4 __attribute__((ext_vector_type(4)));

#define H 56
#define W 56
#define C_IN 32
#define N_OUT 64

__device__ __forceinline__ float q16f(float v) { return (float)(_Float16)v; }

// Single fused kernel: each block stages its own input slab + the full
// weight-fragment table into LDS, then runs the 9-shifted-GEMM MFMA loop.
// Removes prep_kernel, the xpad/wf global round-trip, and the dependent
// second dispatch (round-1 evidence: conv is not latency-bound; the ~30us
// residual above the harness poison-fill is launch/handoff structure).
//
// block = (bx, by, b): 4 oh rows (one per wave) x 32 ow x all 64 n.
// LDS: xT[r=6][colL=34][c=32] f16 (13,056 B)  input slab, zero-padded
//      wT[ij=9][n=64][c=32]  f16 (36,864 B)  A-fragments, [n][c] contiguous
__global__ __launch_bounds__(256, 2) void conv_fused(
    const float* __restrict__ x,       // [16,32,56,56]
    const float* __restrict__ weight,  // [64,32,3,3]
    const float* __restrict__ bias,    // [64]
    float* __restrict__ out)           // [16,64,56,56]
{
    __shared__ _Float16 wT[9 * 64 * 32];
    __shared__ _Float16 xT[6 * 34 * 32];

    const int tid = threadIdx.x;
    const int b   = blockIdx.z;
    const int by  = blockIdx.y;
    const int bx  = blockIdx.x;
    const int ow0 = bx * 24;           // tiles cover ow 0-31 and 24-55

    // ---- stage weights: wT[ij][n][2*c2+{0,1}] = f16(weight[n][c][ij]) ----
    // task p = n*16 + c2; 18 contiguous floats per task (8B-aligned -> float2).
    #pragma unroll
    for (int q = 0; q < 4; ++q) {
        const int p  = tid + q * 256;
        const int n  = p >> 4, c2 = p & 15;
        const float2* wp = (const float2*)(weight + n * 288 + c2 * 18);
        float2 v[9];
        #pragma unroll
        for (int k = 0; k < 9; ++k) v[k] = wp[k];
        #pragma unroll
        for (int ij = 0; ij < 9; ++ij) {
            const float w0 = (ij & 1) ? v[ij >> 1].y : v[ij >> 1].x;            // c = 2*c2
            const int   e  = ij + 9;
            const float w1 = (e & 1) ? v[e >> 1].y : v[e >> 1].x;               // c = 2*c2+1
            const uint32_t pk =
                (uint32_t)__builtin_bit_cast(uint16_t, (_Float16)w0) |
                ((uint32_t)__builtin_bit_cast(uint16_t, (_Float16)w1) << 16);
            ((uint32_t*)wT)[ij * 1024 + n * 16 + c2] = pk;   // 2-way bank max
        }
    }

    // ---- stage input slab: xT[r][colL][c] = f16(x[b][c][by*4-1+r][ow0-1+colL]) ----
    if (tid < 192) {
        const int c  = tid & 31;        // consecutive lanes -> consecutive c
        const int r  = tid >> 5;        // 0..5
        const int ih = by * 4 - 1 + r;
        const int iw0 = ow0 - 1;
        const bool rowok = (unsigned)ih < (unsigned)H;
        const float* xr = x + (((size_t)b * C_IN + c) * H + (rowok ? ih : 0)) * W;
        _Float16* dcol = xT + r * (34 * 32) + c;
        #pragma unroll
        for (int col = 0; col < 34; ++col) {
            const int iw = iw0 + col;
            const bool ok = rowok & ((unsigned)iw < (unsigned)W);
            const float v = ok ? xr[iw] : 0.0f;
            dcol[col * 32] = (_Float16)v;
        }
    }
    __syncthreads();

    // ---- MFMA loop: 9 shifted K=32 GEMMs from LDS ----
    const int lane = tid & 63;
    const int wid  = tid >> 6;          // oh = by*4 + wid, input row r = wid+i
    const int quad = lane >> 4;
    const int px   = lane & 15;
    const int oh   = by * 4 + wid;

    f32x4 acc[2][4] = {{{0,0,0,0},{0,0,0,0},{0,0,0,0},{0,0,0,0}},
                       {{0,0,0,0},{0,0,0,0},{0,0,0,0},{0,0,0,0}}};

    #pragma unroll
    for (int ij = 0; ij < 9; ++ij) {
        const int i = ij / 3, jj = ij - 3 * i;
        // B-frags: B[k=quad*8+t][n=px], 16B contiguous, 16B-aligned
        const _Float16* xb = xT + ((wid + i) * 34 + jj + px) * 32 + quad * 8;
        f16x8 xf0 = *(const f16x8*)xb;
        f16x8 xf1 = *(const f16x8*)(xb + 16 * 32);
        const _Float16* wrow = wT + ij * (64 * 32) + px * 32 + quad * 8;
        #pragma unroll
        for (int nt = 0; nt < 4; ++nt) {
            f16x8 wv = *(const f16x8*)(wrow + nt * (16 * 32));
            acc[0][nt] = __builtin_amdgcn_mfma_f32_16x16x32_f16(wv, xf0, acc[0][nt], 0, 0, 0);
            acc[1][nt] = __builtin_amdgcn_mfma_f32_16x16x32_f16(wv, xf1, acc[1][nt], 0, 0, 0);
        }
    }

    // ---- epilogue: out = q16(acc + q16(bias)); quarter-wave = one 64B line ----
    float qb[4][4];
    #pragma unroll
    for (int nt = 0; nt < 4; ++nt)
        #pragma unroll
        for (int reg = 0; reg < 4; ++reg)
            qb[nt][reg] = q16f(bias[nt * 16 + quad * 4 + reg]);

    #pragma unroll
    for (int xg = 0; xg < 2; ++xg) {
        const int ow = ow0 + 16 * xg + px;
        if (bx == 0 || ow >= 32) {      // overlap cols 24..31 owned by bx==0
            #pragma unroll
            for (int nt = 0; nt < 4; ++nt) {
                #pragma unroll
                for (int reg = 0; reg < 4; ++reg) {
                    const int n = nt * 16 + quad * 4 + reg;
                    out[((size_t)(b * N_OUT + n) * H + oh) * W + ow] =
                        q16f(acc[xg][nt][reg] + qb[nt][reg]);
                }
            }
        }
    }
}

extern "C" void kernel_launch(void* const* d_in, const int* in_sizes, int n_in,
                              void* d_out, int out_size, void* d_ws, size_t ws_size,
                              hipStream_t stream) {
    (void)in_sizes; (void)n_in; (void)d_ws; (void)ws_size; (void)out_size;
    const float* x      = (const float*)d_in[0];
    const float* weight = (const float*)d_in[1];
    const float* bias   = (const float*)d_in[2];
    float* out          = (float*)d_out;

    conv_fused<<<dim3(2, 14, 16), dim3(256), 0, stream>>>(x, weight, bias, out);
}

// Round 3
// 78.281 us; speedup vs baseline: 1.0006x; 1.0006x over previous
//
#include <hip/hip_runtime.h>
#include <stdint.h>

typedef _Float16 f16x8 __attribute__((ext_vector_type(8)));
typedef float    f32x4 __attribute__((ext_vector_type(4)));

#define H 56
#define W 56
#define C_IN 32
#define N_OUT 64
#define CS 40   // padded c-stride in f16 (80 B): 20-dword stride -> 2-way banks (free),
                // and 80 % 16 == 0 keeps ds_read_b128 fragments 16B-aligned.
                // (R2 used 32 -> 64B stride -> 8-way conflict on all 54 frag reads.)

__device__ __forceinline__ float q16f(float v) { return (float)(_Float16)v; }

// Single fused kernel: each block stages its input slab + the full weight
// fragment table into LDS, then runs the 9-shifted-GEMM MFMA loop.
// block = (bx, by, b): 4 oh rows (one per wave) x 32 ow x all 64 n.
// LDS: xT[r=6][colL=34][c=CS] f16 (16,320 B)  input slab, zero-padded
//      wT[ij=9][n=64][c=CS]  f16 (46,080 B)  A-fragments
__global__ __launch_bounds__(256, 2) void conv_fused(
    const float* __restrict__ x,       // [16,32,56,56]
    const float* __restrict__ weight,  // [64,32,3,3]
    const float* __restrict__ bias,    // [64]
    float* __restrict__ out)           // [16,64,56,56]
{
    __shared__ _Float16 wT[9 * 64 * CS];
    __shared__ _Float16 xT[6 * 34 * CS];

    const int tid = threadIdx.x;
    const int b   = blockIdx.z;
    const int by  = blockIdx.y;
    const int bx  = blockIdx.x;
    const int ow0 = bx * 24;           // tiles cover ow 0-31 and 24-55

    // ---- stage weights: wT[ij][n][2*c2+{0,1}] = f16(weight[n][c][ij]) ----
    // task p = n*16 + c2; 18 contiguous floats per task (8B-aligned -> float2).
    #pragma unroll
    for (int q = 0; q < 4; ++q) {
        const int p  = tid + q * 256;
        const int n  = p >> 4, c2 = p & 15;
        const float2* wp = (const float2*)(weight + n * 288 + c2 * 18);
        float2 v[9];
        #pragma unroll
        for (int k = 0; k < 9; ++k) v[k] = wp[k];
        #pragma unroll
        for (int ij = 0; ij < 9; ++ij) {
            const float w0 = (ij & 1) ? v[ij >> 1].y : v[ij >> 1].x;            // c = 2*c2
            const int   e  = ij + 9;
            const float w1 = (e & 1) ? v[e >> 1].y : v[e >> 1].x;               // c = 2*c2+1
            const uint32_t pk =
                (uint32_t)__builtin_bit_cast(uint16_t, (_Float16)w0) |
                ((uint32_t)__builtin_bit_cast(uint16_t, (_Float16)w1) << 16);
            ((uint32_t*)wT)[(ij * 64 + n) * (CS / 2) + c2] = pk;
        }
    }

    // ---- stage input slab: xT[r][colL][c] = f16(x[b][c][by*4-1+r][ow0-1+colL]) ----
    if (tid < 192) {
        const int c  = tid & 31;        // consecutive lanes -> consecutive c
        const int r  = tid >> 5;        // 0..5
        const int ih = by * 4 - 1 + r;
        const int iw0 = ow0 - 1;
        const bool rowok = (unsigned)ih < (unsigned)H;
        const float* xr = x + (((size_t)b * C_IN + c) * H + (rowok ? ih : 0)) * W;
        _Float16* dcol = xT + r * (34 * CS) + c;
        #pragma unroll
        for (int col = 0; col < 34; ++col) {
            const int iw = iw0 + col;
            const bool ok = rowok & ((unsigned)iw < (unsigned)W);
            const float v = ok ? xr[iw] : 0.0f;
            dcol[col * CS] = (_Float16)v;
        }
    }
    __syncthreads();

    // ---- MFMA loop: 9 shifted K=32 GEMMs from LDS ----
    const int lane = tid & 63;
    const int wid  = tid >> 6;          // oh = by*4 + wid, input row r = wid+i
    const int quad = lane >> 4;
    const int px   = lane & 15;
    const int oh   = by * 4 + wid;

    f32x4 acc[2][4] = {{{0,0,0,0},{0,0,0,0},{0,0,0,0},{0,0,0,0}},
                       {{0,0,0,0},{0,0,0,0},{0,0,0,0},{0,0,0,0}}};

    #pragma unroll
    for (int ij = 0; ij < 9; ++ij) {
        const int i = ij / 3, jj = ij - 3 * i;
        // B-frags: B[k=quad*8+t][n=px], 16B contiguous, 16B-aligned
        const _Float16* xb = xT + ((wid + i) * 34 + jj + px) * CS + quad * 8;
        f16x8 xf0 = *(const f16x8*)xb;
        f16x8 xf1 = *(const f16x8*)(xb + 16 * CS);
        const _Float16* wrow = wT + (ij * 64 + px) * CS + quad * 8;
        #pragma unroll
        for (int nt = 0; nt < 4; ++nt) {
            f16x8 wv = *(const f16x8*)(wrow + nt * (16 * CS));
            acc[0][nt] = __builtin_amdgcn_mfma_f32_16x16x32_f16(wv, xf0, acc[0][nt], 0, 0, 0);
            acc[1][nt] = __builtin_amdgcn_mfma_f32_16x16x32_f16(wv, xf1, acc[1][nt], 0, 0, 0);
        }
    }

    // ---- epilogue: out = q16(acc + q16(bias)); quarter-wave = one 64B line ----
    float qb[4][4];
    #pragma unroll
    for (int nt = 0; nt < 4; ++nt)
        #pragma unroll
        for (int reg = 0; reg < 4; ++reg)
            qb[nt][reg] = q16f(bias[nt * 16 + quad * 4 + reg]);

    #pragma unroll
    for (int xg = 0; xg < 2; ++xg) {
        const int ow = ow0 + 16 * xg + px;
        if (bx == 0 || ow >= 32) {      // overlap cols 24..31 owned by bx==0
            #pragma unroll
            for (int nt = 0; nt < 4; ++nt) {
                #pragma unroll
                for (int reg = 0; reg < 4; ++reg) {
                    const int n = nt * 16 + quad * 4 + reg;
                    out[((size_t)(b * N_OUT + n) * H + oh) * W + ow] =
                        q16f(acc[xg][nt][reg] + qb[nt][reg]);
                }
            }
        }
    }
}

extern "C" void kernel_launch(void* const* d_in, const int* in_sizes, int n_in,
                              void* d_out, int out_size, void* d_ws, size_t ws_size,
                              hipStream_t stream) {
    (void)in_sizes; (void)n_in; (void)d_ws; (void)ws_size; (void)out_size;
    const float* x      = (const float*)d_in[0];
    const float* weight = (const float*)d_in[1];
    const float* bias   = (const float*)d_in[2];
    float* out          = (float*)d_out;

    conv_fused<<<dim3(2, 14, 16), dim3(256), 0, stream>>>(x, weight, bias, out);
}

// Round 4
// 78.064 us; speedup vs baseline: 1.0033x; 1.0028x over previous
//
#include <hip/hip_runtime.h>
#include <stdint.h>

typedef _Float16 f16x8 __attribute__((ext_vector_type(8)));
typedef float    f32x4 __attribute__((ext_vector_type(4)));

#define H 56
#define W 56
#define C_IN 32
#define N_OUT 64
#define CS 40   // xT c-stride in f16 (80 B). CS%8==0 keeps b128 frags 16B-aligned;
                // read banks uniform (stride-20-dword, 8 start-groups x 2 lanes);
                // staging ds_write_b16 stride-20-dword -> 4-way (24 instrs, cheap).

__device__ __forceinline__ float q16f(float v) { return (float)(_Float16)v; }

// Tiny kernel 1: pack weights into MFMA A-fragment order (36 KB table).
// dword o = ((ij*4+nt)*64 + lane)*4 + t2
// A[m = nt*16 + (lane&15) -> n][k = (lane>>4)*8 + 2*t2 + {0,1} -> c]
__global__ __launch_bounds__(256) void wpack_kernel(
    const float* __restrict__ weight, uint32_t* __restrict__ wf)
{
    const int o = blockIdx.x * 256 + threadIdx.x;   // < 9216
    const int t2   = o & 3;
    const int lane = (o >> 2) & 63;
    const int u    = o >> 8;
    const int nt   = u & 3, ij = u >> 2;
    const int n    = nt * 16 + (lane & 15);
    const int c0   = (lane >> 4) * 8 + 2 * t2;
    const _Float16 lo = (_Float16)weight[n * 288 + c0 * 9 + ij];
    const _Float16 hi = (_Float16)weight[n * 288 + (c0 + 1) * 9 + ij];
    wf[o] = (uint32_t)__builtin_bit_cast(uint16_t, lo) |
            ((uint32_t)__builtin_bit_cast(uint16_t, hi) << 16);
}

// Kernel 2: conv with in-block input staging (coalesced) + global wf frags.
// block = (bx, by, b): 4 oh rows (one per wave) x 32 ow x all 64 n.
// LDS: xT[r=6][colL=34][c=CS] f16 (16,320 B), zero-padded slab.
__global__ __launch_bounds__(256, 2) void conv_fused(
    const float* __restrict__ x,       // [16,32,56,56]
    const f16x8* __restrict__ wf,      // A-fragment table, L2-hot
    const float* __restrict__ bias,    // [64]
    float* __restrict__ out)           // [16,64,56,56]
{
    __shared__ _Float16 xT[6 * 34 * CS];

    const int tid = threadIdx.x;
    const int b   = blockIdx.z;
    const int by  = blockIdx.y;
    const int bx  = blockIdx.x;
    const int ow0 = bx * 24;           // tiles cover ow 0-31 and 24-55

    // ---- stage input slab, coalesced: lane l = column, half-wave reads one
    // (c, ih) row contiguously (128 B = 2-3 lines), LDS eats the transpose. ----
    {
        const int g = tid >> 5, l = tid & 31;         // l -> slab col 0..31
        const int iw = ow0 - 1 + l;
        const bool iwok = (unsigned)iw < (unsigned)W;
        #pragma unroll
        for (int s = 0; s < 24; ++s) {
            const int task = s * 8 + g;               // 192 (r,c) tasks
            const int r = task >> 5, c = task & 31;
            const int ih = by * 4 - 1 + r;
            const bool ok = iwok & ((unsigned)ih < (unsigned)H);
            const float v = ok ? x[(((size_t)b * C_IN + c) * H + (ok ? ih : 0)) * W + iw]
                               : 0.0f;
            xT[(r * 34 + l) * CS + c] = (_Float16)v;
        }
        // tail columns 32,33 (c-contiguous writes; loads land in lines already
        // touched by the main loop -> L1-hot)
        if (tid < 192) {
            const int r = tid >> 5, c = tid & 31;
            const int ih = by * 4 - 1 + r;
            #pragma unroll
            for (int col = 32; col < 34; ++col) {
                const int iw2 = ow0 - 1 + col;
                const bool ok = ((unsigned)ih < (unsigned)H) &
                                ((unsigned)iw2 < (unsigned)W);
                const float v = ok ? x[(((size_t)b * C_IN + c) * H + (ok ? ih : 0)) * W + iw2]
                                   : 0.0f;
                xT[(r * 34 + col) * CS + c] = (_Float16)v;
            }
        }
    }
    __syncthreads();

    // ---- MFMA loop: 9 shifted K=32 GEMMs; B-frags from LDS, A-frags from wf ----
    const int lane = tid & 63;
    const int wid  = tid >> 6;          // oh = by*4 + wid, slab row r = wid+i
    const int quad = lane >> 4;
    const int px   = lane & 15;
    const int oh   = by * 4 + wid;

    f32x4 acc[2][4] = {{{0,0,0,0},{0,0,0,0},{0,0,0,0},{0,0,0,0}},
                       {{0,0,0,0},{0,0,0,0},{0,0,0,0},{0,0,0,0}}};

    #pragma unroll
    for (int ij = 0; ij < 9; ++ij) {
        const int i = ij / 3, jj = ij - 3 * i;
        const _Float16* xb = xT + ((wid + i) * 34 + jj + px) * CS + quad * 8;
        f16x8 xf0 = *(const f16x8*)xb;                  // ds_read_b128, uniform banks
        f16x8 xf1 = *(const f16x8*)(xb + 16 * CS);
        #pragma unroll
        for (int nt = 0; nt < 4; ++nt) {
            f16x8 wv = wf[(ij * 4 + nt) * 64 + lane];   // dwordx4, L2-hot (36 KB)
            acc[0][nt] = __builtin_amdgcn_mfma_f32_16x16x32_f16(wv, xf0, acc[0][nt], 0, 0, 0);
            acc[1][nt] = __builtin_amdgcn_mfma_f32_16x16x32_f16(wv, xf1, acc[1][nt], 0, 0, 0);
        }
    }

    // ---- epilogue: out = q16(acc + q16(bias)); quarter-wave = one 64B line ----
    float qb[4][4];
    #pragma unroll
    for (int nt = 0; nt < 4; ++nt)
        #pragma unroll
        for (int reg = 0; reg < 4; ++reg)
            qb[nt][reg] = q16f(bias[nt * 16 + quad * 4 + reg]);

    #pragma unroll
    for (int xg = 0; xg < 2; ++xg) {
        const int ow = ow0 + 16 * xg + px;
        if (bx == 0 || ow >= 32) {      // overlap cols 24..31 owned by bx==0
            #pragma unroll
            for (int nt = 0; nt < 4; ++nt) {
                #pragma unroll
                for (int reg = 0; reg < 4; ++reg) {
                    const int n = nt * 16 + quad * 4 + reg;
                    out[((size_t)(b * N_OUT + n) * H + oh) * W + ow] =
                        q16f(acc[xg][nt][reg] + qb[nt][reg]);
                }
            }
        }
    }
}

extern "C" void kernel_launch(void* const* d_in, const int* in_sizes, int n_in,
                              void* d_out, int out_size, void* d_ws, size_t ws_size,
                              hipStream_t stream) {
    (void)in_sizes; (void)n_in; (void)ws_size; (void)out_size;
    const float* x      = (const float*)d_in[0];
    const float* weight = (const float*)d_in[1];
    const float* bias   = (const float*)d_in[2];
    float* out          = (float*)d_out;
    uint32_t* wfp       = (uint32_t*)d_ws;    // 36,864 B

    wpack_kernel<<<dim3(36), dim3(256), 0, stream>>>(weight, wfp);
    conv_fused<<<dim3(2, 14, 16), dim3(256), 0, stream>>>(x, (const f16x8*)wfp, bias, out);
}

// Round 5
// 73.299 us; speedup vs baseline: 1.0686x; 1.0650x over previous
//
#include <hip/hip_runtime.h>
#include <stdint.h>

typedef _Float16 f16x8 __attribute__((ext_vector_type(8)));
typedef float    f32x4 __attribute__((ext_vector_type(4)));

#define H 56
#define W 56
#define C_IN 32
#define N_OUT 64
#define PR 58                 // padded rows, row = ih+1
#define PCOLS 58              // padded cols, col = iw+1 (0 and 57 are the zero pads)
#define XB_BLOCKS (16 * PR)   // 928 transpose blocks
#define NWF 9216              // wf dwords: 9 ij * 4 nt * 64 lane * 4 dw
#define XPAD_BYTES ((size_t)16 * PR * PCOLS * C_IN * 2)   // 3,444,736 B (256-aligned)

__device__ __forceinline__ float q16f(float v) { return (float)(_Float16)v; }

// merged prep: blocks [0,928) transpose x to channel-innermost f16 with zero
// padding; blocks [928,964) pack weights into MFMA A-fragment order.
__global__ __launch_bounds__(256) void prep_kernel(
    const float* __restrict__ x, const float* __restrict__ weight,
    _Float16* __restrict__ xpad, uint32_t* __restrict__ wf)
{
    const int nb  = blockIdx.x;
    const int tid = threadIdx.x;
    if (nb < XB_BLOCKS) {
        // one block = one (b,row): x[b][c][ih][iw] -> xpad[b][row][col][c]
        __shared__ _Float16 sT[PCOLS * 34];   // col stride 34 f16 (17 dw) kills conflicts
        const int b = nb / PR, row = nb % PR, ih = row - 1;
        const bool interior = (unsigned)ih < (unsigned)H;
        if (interior) {
            // zero only the two pad columns (cols 1..56 are fully overwritten)
            if (tid < 32) {
                int col = (tid >> 4) * 57, cd = tid & 15;
                ((uint32_t*)sT)[col * 17 + cd] = 0u;
            }
            __syncthreads();
            #pragma unroll
            for (int k = 0; k < 7; ++k) {       // 7*256 = 1792 = 32c * 56iw
                int idx = k * 256 + tid;
                int c = idx / W, iw = idx - c * W;
                sT[(iw + 1) * 34 + c] = (_Float16)x[((b * C_IN + c) * H + ih) * W + iw];
            }
        } else {
            // halo row: everything zero
            for (int i = tid; i < PCOLS * 17; i += 256) ((uint32_t*)sT)[i] = 0u;
        }
        __syncthreads();
        // write out 928 dwords as 464 coalesced uint2
        uint2* dst = (uint2*)(xpad + ((size_t)b * PR + row) * PCOLS * C_IN);
        for (int i = tid; i < PCOLS * 8; i += 256) {
            int col = i >> 3, cd2 = i & 7;
            const uint32_t* s = &((const uint32_t*)sT)[col * 17 + 2 * cd2];
            uint2 v = { s[0], s[1] };
            dst[i] = v;
        }
    } else {
        // A-frag pack: dword o = ((ij*4+nt)*64 + lane)*4 + t2
        // A[m = nt*16 + (lane&15) -> n][k = (lane>>4)*8 + 2*t2 + {0,1} -> c]
        int o = (nb - XB_BLOCKS) * 256 + tid;           // < 9216
        int t2   = o & 3;
        int lane = (o >> 2) & 63;
        int u    = o >> 8;
        int nt   = u & 3, ij = u >> 2;
        int n    = nt * 16 + (lane & 15);
        int c0   = (lane >> 4) * 8 + 2 * t2;
        _Float16 lo = (_Float16)weight[n * 288 + c0 * 9 + ij];
        _Float16 hi = (_Float16)weight[n * 288 + (c0 + 1) * 9 + ij];
        wf[o] = (uint32_t)__builtin_bit_cast(uint16_t, lo) |
                ((uint32_t)__builtin_bit_cast(uint16_t, hi) << 16);
    }
}

// conv as 9 shifted K=32 GEMMs, no LDS, no barrier (loads pipeline vs MFMA).
// ONE WAVE PER BLOCK: 1 oh row x 32 ow (two 16-px B-frag groups sharing A) x 64 n.
// grid 2*56*16 = 1792 blocks = exactly 7.0 blocks/CU -> perfect load balance
// (R0's 448x4-wave blocks gave 1.75 blocks/CU, 2-vs-1 tail imbalance).
__global__ __launch_bounds__(64, 2) void conv_mfma(
    const _Float16* __restrict__ xpad,   // [16][58][58][32] f16
    const f16x8*    __restrict__ wf,     // A-fragment layout
    const float*    __restrict__ bias,   // [64]
    float* __restrict__ out)             // [16,64,56,56]
{
    const int b    = blockIdx.z;
    const int oh   = blockIdx.y;
    const int bx   = blockIdx.x;
    const int ow0  = bx * 24;            // tiles cover ow 0-31 and 24-55
    const int lane = threadIdx.x;        // 64-thread block = one wave
    const int quad = lane >> 4;
    const int px   = lane & 15;

    // B-frag bases: B[k=c][n=px], k = quad*8+t -> 16 contiguous bytes per load
    const _Float16* xb0 = xpad + (((size_t)b * PR + oh) * PCOLS + ow0 + px) * C_IN + quad * 8;
    const _Float16* xb1 = xb0 + 16 * C_IN;

    f32x4 acc[2][4] = {{{0,0,0,0},{0,0,0,0},{0,0,0,0},{0,0,0,0}},
                       {{0,0,0,0},{0,0,0,0},{0,0,0,0},{0,0,0,0}}};

    #pragma unroll
    for (int ij = 0; ij < 9; ++ij) {
        const int i = ij / 3, jj = ij - 3 * i;
        const int sh = (i * PCOLS + jj) * C_IN;
        f16x8 xf0 = *(const f16x8*)(xb0 + sh);              // dwordx4, L1/L2-hot
        f16x8 xf1 = *(const f16x8*)(xb1 + sh);
        #pragma unroll
        for (int nt = 0; nt < 4; ++nt) {
            f16x8 wv = wf[(ij * 4 + nt) * 64 + lane];       // dwordx4, L1/L2-hot
            acc[0][nt] = __builtin_amdgcn_mfma_f32_16x16x32_f16(wv, xf0, acc[0][nt], 0, 0, 0);
            acc[1][nt] = __builtin_amdgcn_mfma_f32_16x16x32_f16(wv, xf1, acc[1][nt], 0, 0, 0);
        }
    }

    // epilogue: out = q16(acc + q16(bias)); quarter-wave = one full 64B line.
    // overlap columns 24..31 are owned by tile bx==0.
    float qb[4][4];
    #pragma unroll
    for (int nt = 0; nt < 4; ++nt)
        #pragma unroll
        for (int reg = 0; reg < 4; ++reg)
            qb[nt][reg] = q16f(bias[nt * 16 + quad * 4 + reg]);

    #pragma unroll
    for (int xg = 0; xg < 2; ++xg) {
        const int ow = ow0 + 16 * xg + px;
        if (bx == 0 || ow >= 32) {
            #pragma unroll
            for (int nt = 0; nt < 4; ++nt) {
                #pragma unroll
                for (int reg = 0; reg < 4; ++reg) {
                    const int n = nt * 16 + quad * 4 + reg;
                    out[((size_t)(b * N_OUT + n) * H + oh) * W + ow] =
                        q16f(acc[xg][nt][reg] + qb[nt][reg]);
                }
            }
        }
    }
}

extern "C" void kernel_launch(void* const* d_in, const int* in_sizes, int n_in,
                              void* d_out, int out_size, void* d_ws, size_t ws_size,
                              hipStream_t stream) {
    (void)in_sizes; (void)n_in; (void)ws_size; (void)out_size;
    const float* x      = (const float*)d_in[0];
    const float* weight = (const float*)d_in[1];
    const float* bias   = (const float*)d_in[2];
    float* out          = (float*)d_out;

    _Float16* xpad = (_Float16*)d_ws;
    uint32_t* wfp  = (uint32_t*)((char*)d_ws + XPAD_BYTES);   // 36,864 B

    prep_kernel<<<dim3(XB_BLOCKS + NWF / 256), dim3(256), 0, stream>>>(x, weight, xpad, wfp);
    conv_mfma<<<dim3(2, 56, 16), dim3(64), 0, stream>>>(xpad, (const f16x8*)wfp, bias, out);
}

// Round 6
// 71.897 us; speedup vs baseline: 1.0894x; 1.0195x over previous
//
#include <hip/hip_runtime.h>
#include <stdint.h>

typedef _Float16 f16x8 __attribute__((ext_vector_type(8)));
typedef float    f32x4 __attribute__((ext_vector_type(4)));

#define H 56
#define W 56
#define C_IN 32
#define N_OUT 64
#define PR 58                 // padded rows, row = ih+1
#define PCOLS 58              // padded cols, col = iw+1 (0 and 57 are the zero pads)
#define XB_BLOCKS (16 * PR)   // 928 transpose blocks
#define NWF 9216              // wf dwords: 9 ij * 4 nt * 64 lane * 4 dw
#define XPAD_BYTES ((size_t)16 * PR * PCOLS * C_IN * 2)   // 3,444,736 B (256-aligned)

__device__ __forceinline__ float q16f(float v) { return (float)(_Float16)v; }

// merged prep: blocks [0,928) transpose x to channel-innermost f16 with zero
// padding; blocks [928,964) pack weights into MFMA A-fragment order.
__global__ __launch_bounds__(256) void prep_kernel(
    const float* __restrict__ x, const float* __restrict__ weight,
    _Float16* __restrict__ xpad, uint32_t* __restrict__ wf)
{
    const int nb  = blockIdx.x;
    const int tid = threadIdx.x;
    if (nb < XB_BLOCKS) {
        // one block = one (b,row): x[b][c][ih][iw] -> xpad[b][row][col][c]
        __shared__ _Float16 sT[PCOLS * 34];   // col stride 34 f16 (17 dw) kills conflicts
        const int b = nb / PR, row = nb % PR, ih = row - 1;
        const bool interior = (unsigned)ih < (unsigned)H;
        if (interior) {
            // zero only the two pad columns (cols 1..56 are fully overwritten)
            if (tid < 32) {
                int col = (tid >> 4) * 57, cd = tid & 15;
                ((uint32_t*)sT)[col * 17 + cd] = 0u;
            }
            __syncthreads();
            #pragma unroll
            for (int k = 0; k < 7; ++k) {       // 7*256 = 1792 = 32c * 56iw
                int idx = k * 256 + tid;
                int c = idx / W, iw = idx - c * W;
                sT[(iw + 1) * 34 + c] = (_Float16)x[((b * C_IN + c) * H + ih) * W + iw];
            }
        } else {
            // halo row: everything zero
            for (int i = tid; i < PCOLS * 17; i += 256) ((uint32_t*)sT)[i] = 0u;
        }
        __syncthreads();
        // write out 928 dwords as 464 coalesced uint2
        uint2* dst = (uint2*)(xpad + ((size_t)b * PR + row) * PCOLS * C_IN);
        for (int i = tid; i < PCOLS * 8; i += 256) {
            int col = i >> 3, cd2 = i & 7;
            const uint32_t* s = &((const uint32_t*)sT)[col * 17 + 2 * cd2];
            uint2 v = { s[0], s[1] };
            dst[i] = v;
        }
    } else {
        // A-frag pack: dword o = ((ij*4+nt)*64 + lane)*4 + t2
        // A[m = nt*16 + (lane&15) -> n][k = (lane>>4)*8 + 2*t2 + {0,1} -> c]
        int o = (nb - XB_BLOCKS) * 256 + tid;           // < 9216
        int t2   = o & 3;
        int lane = (o >> 2) & 63;
        int u    = o >> 8;
        int nt   = u & 3, ij = u >> 2;
        int n    = nt * 16 + (lane & 15);
        int c0   = (lane >> 4) * 8 + 2 * t2;
        _Float16 lo = (_Float16)weight[n * 288 + c0 * 9 + ij];
        _Float16 hi = (_Float16)weight[n * 288 + (c0 + 1) * 9 + ij];
        wf[o] = (uint32_t)__builtin_bit_cast(uint16_t, lo) |
                ((uint32_t)__builtin_bit_cast(uint16_t, hi) << 16);
    }
}

// conv as 9 shifted K=32 GEMMs, no LDS, no barrier.
// wave = 1 oh row x 32 ow (two 16-px B-frag groups sharing A) x 64 n.
// R0 configuration: 448 blocks x 4 waves — empirically best across
// occupancy (R1), balance (R5), fused (R2-R4) variants.
__global__ __launch_bounds__(256, 2) void conv_mfma(
    const _Float16* __restrict__ xpad,   // [16][58][58][32] f16
    const f16x8*    __restrict__ wf,     // A-fragment layout
    const float*    __restrict__ bias,   // [64]
    float* __restrict__ out)             // [16,64,56,56]
{
    const int tid  = threadIdx.x;
    const int b    = blockIdx.z;
    const int oh   = blockIdx.y * 4 + (tid >> 6);
    const int bx   = blockIdx.x;
    const int ow0  = bx * 24;            // tiles cover ow 0-31 and 24-55
    const int lane = tid & 63;
    const int quad = lane >> 4;
    const int px   = lane & 15;

    // B-frag bases: B[k=c][n=px], k = quad*8+t -> 16 contiguous bytes per load
    const _Float16* xb0 = xpad + (((size_t)b * PR + oh) * PCOLS + ow0 + px) * C_IN + quad * 8;
    const _Float16* xb1 = xb0 + 16 * C_IN;

    f32x4 acc[2][4] = {{{0,0,0,0},{0,0,0,0},{0,0,0,0},{0,0,0,0}},
                       {{0,0,0,0},{0,0,0,0},{0,0,0,0},{0,0,0,0}}};

    #pragma unroll
    for (int ij = 0; ij < 9; ++ij) {
        const int i = ij / 3, jj = ij - 3 * i;
        const int sh = (i * PCOLS + jj) * C_IN;
        f16x8 xf0 = *(const f16x8*)(xb0 + sh);              // dwordx4, L1/L2-hot
        f16x8 xf1 = *(const f16x8*)(xb1 + sh);
        #pragma unroll
        for (int nt = 0; nt < 4; ++nt) {
            f16x8 wv = wf[(ij * 4 + nt) * 64 + lane];       // dwordx4, L1/L2-hot
            acc[0][nt] = __builtin_amdgcn_mfma_f32_16x16x32_f16(wv, xf0, acc[0][nt], 0, 0, 0);
            acc[1][nt] = __builtin_amdgcn_mfma_f32_16x16x32_f16(wv, xf1, acc[1][nt], 0, 0, 0);
        }
    }

    // epilogue: out = q16(acc + q16(bias)); quarter-wave = one full 64B line.
    // overlap columns 24..31 are owned by tile bx==0.
    float qb[4][4];
    #pragma unroll
    for (int nt = 0; nt < 4; ++nt)
        #pragma unroll
        for (int reg = 0; reg < 4; ++reg)
            qb[nt][reg] = q16f(bias[nt * 16 + quad * 4 + reg]);

    #pragma unroll
    for (int xg = 0; xg < 2; ++xg) {
        const int ow = ow0 + 16 * xg + px;
        if (bx == 0 || ow >= 32) {
            #pragma unroll
            for (int nt = 0; nt < 4; ++nt) {
                #pragma unroll
                for (int reg = 0; reg < 4; ++reg) {
                    const int n = nt * 16 + quad * 4 + reg;
                    out[((size_t)(b * N_OUT + n) * H + oh) * W + ow] =
                        q16f(acc[xg][nt][reg] + qb[nt][reg]);
                }
            }
        }
    }
}

extern "C" void kernel_launch(void* const* d_in, const int* in_sizes, int n_in,
                              void* d_out, int out_size, void* d_ws, size_t ws_size,
                              hipStream_t stream) {
    (void)in_sizes; (void)n_in; (void)ws_size; (void)out_size;
    const float* x      = (const float*)d_in[0];
    const float* weight = (const float*)d_in[1];
    const float* bias   = (const float*)d_in[2];
    float* out          = (float*)d_out;

    _Float16* xpad = (_Float16*)d_ws;
    uint32_t* wfp  = (uint32_t*)((char*)d_ws + XPAD_BYTES);   // 36,864 B

    prep_kernel<<<dim3(XB_BLOCKS + NWF / 256), dim3(256), 0, stream>>>(x, weight, xpad, wfp);
    conv_mfma<<<dim3(2, 14, 16), dim3(256), 0, stream>>>(xpad, (const f16x8*)wfp, bias, out);
}